// Round 11
// baseline (505.539 us; speedup 1.0000x reference)
//
#include <hip/hip_runtime.h>
#include <math.h>

#define H_ 128
#define W_ 128
#define C_ 64
#define O_ 64
#define B_ 8
#define K2_ 9
#define HWSZ (H_*W_)

// vector global loads with only 4-byte alignment guarantee.
typedef float f2u __attribute__((ext_vector_type(2), aligned(4)));
typedef float f4u __attribute__((ext_vector_type(4), aligned(4)));

// ---------------------------------------------------------------------------
// Kernel P: weight prep.
//  wt  (K2, C, O) : sample-GEMM weights, contiguous in o -> clean s_load.
//  wom (C, 4, 64) : offset(18)+mask(9) conv weights, repacked per
//                   (channel, o-quarter): 63 floats = quarter's 7 outs x 9
//                   taps + 1 zero pad -> exactly 16 dwordx4 per (c,quarter).
// ---------------------------------------------------------------------------
__global__ __launch_bounds__(256) void prep_weights_k(
    const float* __restrict__ w, const float* __restrict__ w_off,
    const float* __restrict__ w_mod, float* __restrict__ wt,
    float* __restrict__ wom) {
    int id = blockIdx.x * 256 + threadIdx.x;
    if (id < K2_ * C_ * O_) {              // id = k*C*O + c*O + o
        int o = id & (O_ - 1);
        int c = (id >> 6) & (C_ - 1);
        int k = id / (C_ * O_);
        wt[id] = w[(o * C_ + c) * K2_ + k];
    }
    int id2 = id - K2_ * C_ * O_;
    if (id2 >= 0 && id2 < C_ * 256) {      // id2 = c*256 + q*64 + r
        int c = id2 >> 8;
        int rr = id2 & 255;
        int q = rr >> 6;
        int r = rr & 63;
        float v = 0.0f;
        if (r < 63) {
            int tt = q * 7 + r / 9;        // global output row 0..27
            int k  = r % 9;
            if (tt < 18)      v = w_off[(tt * C_ + c) * K2_ + k];
            else if (tt < 27) v = w_mod[((tt - 18) * C_ + c) * K2_ + k];
            // tt == 27: zero pad
        }
        wom[id2] = v;
    }
}

// ---------------------------------------------------------------------------
// Kernel A6: offset/mask 3x3 conv, scalar-latency-chain eliminated.
// History: A stuck 115-160us across r8 (weight volume /4: -10%), r9 (TA
// instrs /3: -6%), r10 (2x TLP: -35% WORSE). Remaining invariant: one
// blocking s_load weight burst per c-iter -- unpipelineable because 2x63
// weight floats don't fit the ~100 free SGPRs; fused-r4 arithmetic puts A's
// VALUBusy at ~26% (stall ~3x FMA time).
// A6 fix: weights -> VGPRs. Vector dwordx4 loads (uniform addr = 1 line/wave,
// trivial TA) into explicitly double-buffered Wa/Wb[16] f4u; taps double-
// buffered Ta/Tb likewise; c-loop unrolled by 2 so all buffer indices are
// compile-time (rule #20). mbcnt_lo(0,0) poisons the weight pointer's
// uniformity so LLVM can't re-scalarize the loads back into the s_load path.
// Block 512 = 128 cols x 4 o-quarters, thread = 2 px (rows h0,h0+1), full
// 64-c loop. ~200 VGPR -> __launch_bounds__(512,2), 8 waves/CU; latency
// hidden by SW pipelining, not TLP.
// ---------------------------------------------------------------------------
__global__ __launch_bounds__(512, 2) void conv_offmask_k(
    const float* __restrict__ x,
    const float* __restrict__ wom, const float* __restrict__ b_off,
    const float* __restrict__ b_mod,
    float* __restrict__ pyA, float* __restrict__ pxA, float* __restrict__ mA) {
    __shared__ float AO[28 * 256];         // 28.7 KB: quarter-sum exchange

    int b     = blockIdx.x & 7;            // batch -> XCD (L2 locality)
    int strip = blockIdx.x >> 3;           // 0..63 : 2-row strip
    int tid   = threadIdx.x;
    int t     = tid & 127;                 // pixel col
    int oq    = tid >> 7;                  // 0..3 : output quarter (wave-uniform)
    int qu    = __builtin_amdgcn_readfirstlane(oq);
    int qoff  = qu * 64;
    int h0    = strip * 2;

    // formally-divergent zero: keeps weight loads on the VECTOR path
    int lz = __builtin_amdgcn_mbcnt_lo(0u, 0u);
    const float* womv = wom + lz;

    // stencil rows h0-1..h0+2 (clamped + validity); rows h0,h0+1 always valid
    int   yc0 = max(h0 - 1, 0);
    int   yc3 = min(h0 + 2, H_ - 1);
    float vv[4];
    vv[0] = (h0 > 0) ? 1.0f : 0.0f;
    vv[1] = 1.0f;
    vv[2] = 1.0f;
    vv[3] = (h0 + 2 < H_) ? 1.0f : 0.0f;

    // stencil cols t-1..t+1 from one dwordx4 at lc (edge lanes shifted)
    int  lc   = min(max(t - 1, 0), W_ - 4);
    bool t0   = (t == 0);
    bool t126 = (t == 126);
    bool t127 = (t == 127);

    const float* xb = x + b * C_ * HWSZ;

    float acc[7][2];
#pragma unroll
    for (int o = 0; o < 7; o++) { acc[o][0] = 0.0f; acc[o][1] = 0.0f; }

#define WGET(WW, WI)                                                           \
    (((WI) & 3) == 0 ? WW[(WI) >> 2].x : ((WI) & 3) == 1 ? WW[(WI) >> 2].y :   \
     ((WI) & 3) == 2 ? WW[(WI) >> 2].z : WW[(WI) >> 2].w)

#define WLOAD(DST, CC)                                                         \
    {                                                                          \
        const float* wp_ = womv + (CC) * 256 + qoff;                           \
        _Pragma("unroll")                                                      \
        for (int j = 0; j < 16; j++) DST[j] = *(const f4u*)(wp_ + 4 * j);      \
    }

#define TLOAD(DST, CC)                                                         \
    {                                                                          \
        const float* xc_ = xb + (CC) * HWSZ;                                   \
        DST[0] = *(const f4u*)(xc_ + yc0 * W_ + lc);                           \
        DST[1] = *(const f4u*)(xc_ + h0 * W_ + lc);                            \
        DST[2] = *(const f4u*)(xc_ + (h0 + 1) * W_ + lc);                      \
        DST[3] = *(const f4u*)(xc_ + yc3 * W_ + lc);                           \
    }

#define FMABODY(WW, TT)                                                        \
    {                                                                          \
        float v[4][3];                                                         \
        _Pragma("unroll")                                                      \
        for (int r = 0; r < 4; r++) {                                          \
            float l0 = TT[r].x, l1 = TT[r].y, l2 = TT[r].z, l3 = TT[r].w;      \
            float vm = vv[r];                                                  \
            v[r][0] = (t0 ? 0.0f : (t127 ? l2 : (t126 ? l1 : l0))) * vm;       \
            v[r][1] = (t0 ? l0   : (t127 ? l3 : (t126 ? l2 : l1))) * vm;       \
            v[r][2] = (t0 ? l1   : (t127 ? 0.0f : (t126 ? l3 : l2))) * vm;     \
        }                                                                      \
        _Pragma("unroll")                                                      \
        for (int o = 0; o < 7; o++) {                                          \
            _Pragma("unroll")                                                  \
            for (int kk = 0; kk < 9; kk++) {                                   \
                const int wi = o * 9 + kk;                                     \
                const int ki = kk / 3, kj = kk % 3;                            \
                float wv = WGET(WW, wi);                                       \
                acc[o][0] += v[ki][kj] * wv;                                   \
                acc[o][1] += v[ki + 1][kj] * wv;                               \
            }                                                                  \
        }                                                                      \
    }

    f4u Wa[16], Wb[16], Ta[4], Tb[4];
    WLOAD(Wa, 0)
    TLOAD(Ta, 0)
    for (int cc = 0; cc < 32; cc++) {
        int ce = 2 * cc;
        WLOAD(Wb, ce + 1)                  // prefetch odd c
        TLOAD(Tb, ce + 1)
        FMABODY(Wa, Ta)                    // even c (loads in flight above)
        int cn = (cc < 31) ? ce + 2 : 63;  // harmless reload on last iter
        WLOAD(Wa, cn)                      // prefetch next even c
        TLOAD(Ta, cn)
        FMABODY(Wb, Tb)                    // odd c
    }
#undef FMABODY
#undef TLOAD
#undef WLOAD
#undef WGET

    // quarter sums -> LDS (rows 0..27; row 27 = zero-pad output, never read)
#pragma unroll
    for (int o = 0; o < 7; o++) {
        AO[(qu * 7 + o) * 256 + t]       = acc[o][0];
        AO[(qu * 7 + o) * 256 + 128 + t] = acc[o][1];
    }
    __syncthreads();

    // epilogue: 256 threads, 1 pixel each, all 9 k's -> coords out
    if (tid < 256) {
        int px = tid;                      // 0..127 row h0, 128..255 row h0+1
        int hh = h0 + (px >> 7);
        int ww = px & 127;
        int p  = hh * W_ + ww;
#pragma unroll
        for (int k = 0; k < 9; k++) {
            float dy = AO[(2 * k) * 256 + px]     + b_off[2 * k];
            float dx = AO[(2 * k + 1) * 256 + px] + b_off[2 * k + 1];
            float mm = AO[(18 + k) * 256 + px]    + b_mod[k];
            float mask = 2.0f / (1.0f + __expf(-mm));
            float py = dy + (float)hh - 1.0f + (float)(k / 3);
            float px_ = dx + (float)ww - 1.0f + (float)(k % 3);
            int idx = (b * 9 + k) * HWSZ + p;
            pyA[idx] = py;
            pxA[idx] = px_;
            mA[idx] = mask;
        }
    }
}

// ---------------------------------------------------------------------------
// Kernel B (round-3 version, verbatim): bilinear sample + reduction GEMM,
// column-pair merged dwordx2 gathers. Measured 180us = TA roofline for this
// divergence pattern (~47 cy/wave-gather). Three LDS-staging attempts
// (r2/r6/r7) all lost to it on VALU/addressing overhead -- do not revisit.
// ---------------------------------------------------------------------------
__global__ __launch_bounds__(512) void sample_gemm_k(
    const float* __restrict__ x,
    const float* __restrict__ pyA, const float* __restrict__ pxA,
    const float* __restrict__ mA, const float* __restrict__ wt,
    const float* __restrict__ bias, float* __restrict__ out) {
    __shared__ float red[O_ * 256];            // 64 KB

    int b     = blockIdx.x & 7;
    int strip = blockIdx.x >> 3;
    int tid   = threadIdx.x;
    int t     = tid & 255;
    int half  = tid >> 8;
    int c0    = __builtin_amdgcn_readfirstlane(half << 5);  // wave-uniform SGPR
    int p     = strip * 256 + t;

    float acc[O_];
#pragma unroll
    for (int o = 0; o < O_; o++) acc[o] = 0.0f;

    const float* xb = x + (b * C_ + c0) * HWSZ;

    for (int k = 0; k < 9; k++) {
        int idx = (b * 9 + k) * HWSZ + p;
        float py = pyA[idx];
        float px = pxA[idx];
        float m  = mA[idx];

        float y0f = floorf(py), x0f = floorf(px);
        float wy = py - y0f, wx = px - x0f;
        int y0 = (int)y0f, x0 = (int)x0f;
        int y1 = y0 + 1;
        float vy0 = (y0 >= 0 && y0 < H_) ? 1.0f : 0.0f;
        float vy1 = (y1 >= 0 && y1 < H_) ? 1.0f : 0.0f;
        float vx0 = (x0 >= 0 && x0 < W_) ? 1.0f : 0.0f;
        float vx1 = (x0 >= -1 && x0 < W_ - 1) ? 1.0f : 0.0f;
        int y0c = min(max(y0, 0), H_ - 1), y1c = min(max(y1, 0), H_ - 1);

        float w00 = (1.0f - wy) * (1.0f - wx) * vy0 * vx0 * m;
        float w01 = (1.0f - wy) * wx * vy0 * vx1 * m;
        float w10 = wy * (1.0f - wx) * vy1 * vx0 * m;
        float w11 = wy * wx * vy1 * vx1 * m;

        // column-pair merge: one 8B load per row covers both x-taps.
        int lc   = min(max(x0, 0), W_ - 2);    // 0..126, load [lc, lc+1]
        bool xlo = (x0 < 0);                   // v01 lives at f.x
        bool xhi = (x0 > W_ - 2);              // v00 lives at f.y
        float a00 = xhi ? 0.0f : (xlo ? w01 : w00);
        float a01 = xlo ? 0.0f : (xhi ? w00 : w01);
        float a10 = xhi ? 0.0f : (xlo ? w11 : w10);
        float a11 = xlo ? 0.0f : (xhi ? w10 : w11);

        int r0 = y0c * W_ + lc;
        int r1 = y1c * W_ + lc;

        const float* wp = wt + k * (C_ * O_) + c0 * O_;   // uniform -> s_load
        for (int c = 0; c < 32; c++) {
            const float* xc = xb + c * HWSZ;
            f2u f0 = *(const f2u*)(xc + r0);
            f2u f1 = *(const f2u*)(xc + r1);
            float s = a00 * f0.x + a01 * f0.y + a10 * f1.x + a11 * f1.y;
            const float* wpc = wp + c * O_;
#pragma unroll
            for (int o = 0; o < O_; o++) acc[o] += s * wpc[o];
        }
    }

    if (half) {
#pragma unroll
        for (int o = 0; o < O_; o++) red[o * 256 + t] = acc[o];  // stride-1
    }
    __syncthreads();
    if (!half) {
        int obase = b * O_ * HWSZ + p;
#pragma unroll
        for (int o = 0; o < O_; o++)
            out[obase + o * HWSZ] = acc[o] + red[o * 256 + t] + bias[o];
    }
}

// ---------------------------------------------------------------------------
extern "C" void kernel_launch(void* const* d_in, const int* in_sizes, int n_in,
                              void* d_out, int out_size, void* d_ws, size_t ws_size,
                              hipStream_t stream) {
    const float* x     = (const float*)d_in[0];
    const float* w_off = (const float*)d_in[1];
    const float* b_off = (const float*)d_in[2];
    const float* w_mod = (const float*)d_in[3];
    const float* b_mod = (const float*)d_in[4];
    const float* w     = (const float*)d_in[5];
    const float* bias  = (const float*)d_in[6];
    float* out = (float*)d_out;

    const int nCoord = B_ * K2_ * HWSZ;   // 1,179,648
    float* pyA = (float*)d_ws;
    float* pxA = pyA + nCoord;
    float* mA  = pxA + nCoord;
    float* wt  = mA + nCoord;             // 36,864 floats
    float* wom = wt + K2_ * C_ * O_;      // 16,384 floats (C*4*64)

    const int nPrep = K2_ * C_ * O_ + C_ * 256;   // 53,248
    hipLaunchKernelGGL(prep_weights_k, dim3((nPrep + 255) / 256), dim3(256),
                       0, stream, w, w_off, w_mod, wt, wom);
    hipLaunchKernelGGL(conv_offmask_k, dim3(512), dim3(512), 0, stream,
                       x, wom, b_off, b_mod, pyA, pxA, mA);
    hipLaunchKernelGGL(sample_gemm_k, dim3(512), dim3(512), 0, stream,
                       x, pyA, pxA, mA, wt, bias, out);
}